// Round 2
// baseline (274.272 us; speedup 1.0000x reference)
//
#include <hip/hip_runtime.h>

#define SCALE 0.57735026918962576f  // 1/sqrt(3)

// LDS float offsets. Per-matrix layout: [5 segs][6 rows][8 floats]
// row = [w0 w1 w2 w3 w4 w5 bias pad], seg stride 52 -> 5 seg bases land on
// disjoint bank quads (0,20,8,28,16 mod 32) => conflict-free broadcast reads.
#define OFF_WQ 0      // 260 floats
#define OFF_WK 260    // bases mod 32: 4,24,12,0,20
#define OFF_WV 520    // bases mod 32: 8,28,16,4,24
#define OFF_WO 780    // [6][8]
#define OFF_BO 828    // [8]
#define LDS_FLOATS 836

// DPP row rotate: lane i <- lane ((i +/- n) & 15) within its 16-lane row.
// Direction is irrelevant: score-step j and PV-step j use the same rotation,
// so probability slot j always pairs with the matching key/value.
#define ROR(v, n) __int_as_float(__builtin_amdgcn_mov_dpp(__float_as_int(v), 0x120 + (n), 0xF, 0xF, true))

__global__ __launch_bounds__(256) void attn_seg_kernel(
    const float* __restrict__ x,
    const float* __restrict__ Wq, const float* __restrict__ bq,
    const float* __restrict__ Wk, const float* __restrict__ bk,
    const float* __restrict__ Wv, const float* __restrict__ bv,
    const float* __restrict__ Wo, const float* __restrict__ bo,
    float* __restrict__ out, int total)
{
    __shared__ __align__(16) float lds[LDS_FLOATS];
    const int t = threadIdx.x;

    // ---- stage weights into LDS ----
    if (t < 180) {
        unsigned sg = (unsigned)t / 36u, r = (unsigned)t - sg * 36u;
        unsigned o = r / 6u, d = r - o * 6u;
        int dst = (int)(sg * 52u + o * 8u + d);
        lds[OFF_WQ + dst] = Wq[t];
        lds[OFF_WK + dst] = Wk[t];
        lds[OFF_WV + dst] = Wv[t];
    }
    if (t < 30) {
        unsigned sg = (unsigned)t / 6u, o = (unsigned)t - sg * 6u;
        int dst = (int)(sg * 52u + o * 8u + 6u);   // bias in slot 6 of its row
        lds[OFF_WQ + dst] = bq[t];
        lds[OFF_WK + dst] = bk[t];
        lds[OFF_WV + dst] = bv[t];
    }
    if (t < 36) {
        unsigned o = (unsigned)t / 6u, d = (unsigned)t - o * 6u;
        lds[OFF_WO + o * 8u + d] = Wo[t];
    }
    if (t < 6) lds[OFF_BO + t] = bo[t];

    const int s = t & 15;   // sequence position within batch element
    // SEG = [0, 1*5, 2*3, 3, 4*6]
    const int seg = (s == 0) ? 0 : (s < 6) ? 1 : (s < 9) ? 2 : (s == 9) ? 3 : 4;

    const int pos = blockIdx.x * 256 + t;   // global flat (b*16+s)
    const bool valid = pos < total;
    float x0=0.f,x1=0.f,x2=0.f,x3=0.f,x4=0.f,x5=0.f;
    if (valid) {
        const float* xp = x + (size_t)pos * 6;   // contiguous 24B per thread
        float2 a = *(const float2*)(xp);
        float2 b = *(const float2*)(xp + 2);
        float2 c = *(const float2*)(xp + 4);
        x0=a.x; x1=a.y; x2=b.x; x3=b.y; x4=c.x; x5=c.y;
    }

    __syncthreads();   // weights visible

    // ---- per-position Q,K,V projections (6x6 each), bias folded in ----
    float q0,q1,q2,q3,q4,q5, k0,k1,k2,k3,k4,k5, v0,v1,v2,v3,v4,v5;
    {
        const float* W = &lds[OFF_WQ + seg * 52];
        float qq[6];
        #pragma unroll
        for (int o = 0; o < 6; o++) {
            float4 wa = *(const float4*)(W + o * 8);
            float4 wb = *(const float4*)(W + o * 8 + 4);
            qq[o] = wb.z + x0*wa.x + x1*wa.y + x2*wa.z + x3*wa.w + x4*wb.x + x5*wb.y;
        }
        q0=qq[0]*SCALE; q1=qq[1]*SCALE; q2=qq[2]*SCALE;
        q3=qq[3]*SCALE; q4=qq[4]*SCALE; q5=qq[5]*SCALE;
    }
    {
        const float* W = &lds[OFF_WK + seg * 52];
        float kk[6];
        #pragma unroll
        for (int o = 0; o < 6; o++) {
            float4 wa = *(const float4*)(W + o * 8);
            float4 wb = *(const float4*)(W + o * 8 + 4);
            kk[o] = wb.z + x0*wa.x + x1*wa.y + x2*wa.z + x3*wa.w + x4*wb.x + x5*wb.y;
        }
        k0=kk[0]; k1=kk[1]; k2=kk[2]; k3=kk[3]; k4=kk[4]; k5=kk[5];
    }
    {
        const float* W = &lds[OFF_WV + seg * 52];
        float vv[6];
        #pragma unroll
        for (int o = 0; o < 6; o++) {
            float4 wa = *(const float4*)(W + o * 8);
            float4 wb = *(const float4*)(W + o * 8 + 4);
            vv[o] = wb.z + x0*wa.x + x1*wa.y + x2*wa.z + x3*wa.w + x4*wb.x + x5*wb.y;
        }
        v0=vv[0]; v1=vv[1]; v2=vv[2]; v3=vv[3]; v4=vv[4]; v5=vv[5];
    }

    // ---- scores via DPP row-rotate (no LDS): step j reads lane (i+j)&15 ----
    float sc0[16], sc1[16];
    sc0[0] = q0*k0 + q1*k1 + q2*k2;
    sc1[0] = q3*k3 + q4*k4 + q5*k5;
    #define SCORE_STEP(J) { \
        float a0=ROR(k0,J), a1=ROR(k1,J), a2=ROR(k2,J); \
        float a3=ROR(k3,J), a4=ROR(k4,J), a5=ROR(k5,J); \
        sc0[J] = q0*a0 + q1*a1 + q2*a2; \
        sc1[J] = q3*a3 + q4*a4 + q5*a5; }
    SCORE_STEP(1)  SCORE_STEP(2)  SCORE_STEP(3)  SCORE_STEP(4)
    SCORE_STEP(5)  SCORE_STEP(6)  SCORE_STEP(7)  SCORE_STEP(8)
    SCORE_STEP(9)  SCORE_STEP(10) SCORE_STEP(11) SCORE_STEP(12)
    SCORE_STEP(13) SCORE_STEP(14) SCORE_STEP(15)
    #undef SCORE_STEP

    // ---- softmax (max-subtracted) ----
    float m0 = sc0[0], m1 = sc1[0];
    #pragma unroll
    for (int k = 1; k < 16; k++) { m0 = fmaxf(m0, sc0[k]); m1 = fmaxf(m1, sc1[k]); }
    float sum0 = 0.f, sum1 = 0.f;
    #pragma unroll
    for (int k = 0; k < 16; k++) {
        float e0 = __expf(sc0[k] - m0); sc0[k] = e0; sum0 += e0;
        float e1 = __expf(sc1[k] - m1); sc1[k] = e1; sum1 += e1;
    }
    const float inv0 = __builtin_amdgcn_rcpf(sum0);
    const float inv1 = __builtin_amdgcn_rcpf(sum1);

    // ---- ctx = P V via the same DPP rotation ----
    float c0,c1,c2,c3,c4,c5;
    c0 = sc0[0]*v0; c1 = sc0[0]*v1; c2 = sc0[0]*v2;
    c3 = sc1[0]*v3; c4 = sc1[0]*v4; c5 = sc1[0]*v5;
    #define PV_STEP(J) { \
        float b0=ROR(v0,J), b1=ROR(v1,J), b2=ROR(v2,J); \
        float b3=ROR(v3,J), b4=ROR(v4,J), b5=ROR(v5,J); \
        c0 += sc0[J]*b0; c1 += sc0[J]*b1; c2 += sc0[J]*b2; \
        c3 += sc1[J]*b3; c4 += sc1[J]*b4; c5 += sc1[J]*b5; }
    PV_STEP(1)  PV_STEP(2)  PV_STEP(3)  PV_STEP(4)
    PV_STEP(5)  PV_STEP(6)  PV_STEP(7)  PV_STEP(8)
    PV_STEP(9)  PV_STEP(10) PV_STEP(11) PV_STEP(12)
    PV_STEP(13) PV_STEP(14) PV_STEP(15)
    #undef PV_STEP

    c0 *= inv0; c1 *= inv0; c2 *= inv0;
    c3 *= inv1; c4 *= inv1; c5 *= inv1;

    // ---- output projection: out[i] = bo[i] + sum_j ctx[j] * Wo[i][j] ----
    float4 bo4 = *(const float4*)&lds[OFF_BO];
    float2 bo2 = *(const float2*)&lds[OFF_BO + 4];
    float bos[6] = {bo4.x, bo4.y, bo4.z, bo4.w, bo2.x, bo2.y};
    float o_[6];
    #pragma unroll
    for (int o = 0; o < 6; o++) {
        float4 w4 = *(const float4*)&lds[OFF_WO + o * 8];
        float2 w2 = *(const float2*)&lds[OFF_WO + o * 8 + 4];
        o_[o] = bos[o] + c0*w4.x + c1*w4.y + c2*w4.z + c3*w4.w + c4*w2.x + c5*w2.y;
    }

    if (valid) {
        float* op = out + (size_t)pos * 6;
        *(float2*)(op)     = make_float2(o_[0], o_[1]);
        *(float2*)(op + 2) = make_float2(o_[2], o_[3]);
        *(float2*)(op + 4) = make_float2(o_[4], o_[5]);
    }
}

extern "C" void kernel_launch(void* const* d_in, const int* in_sizes, int n_in,
                              void* d_out, int out_size, void* d_ws, size_t ws_size,
                              hipStream_t stream) {
    const float* x  = (const float*)d_in[0];
    const float* Wq = (const float*)d_in[1];
    const float* bq = (const float*)d_in[2];
    const float* Wk = (const float*)d_in[3];
    const float* bk = (const float*)d_in[4];
    const float* Wv = (const float*)d_in[5];
    const float* bv = (const float*)d_in[6];
    const float* Wo = (const float*)d_in[7];
    const float* bo = (const float*)d_in[8];
    float* out = (float*)d_out;

    const int total = in_sizes[0] / 6;          // B*16 positions
    const int grid  = (total + 255) / 256;      // 16 batch elems / block
    attn_seg_kernel<<<grid, 256, 0, stream>>>(x, Wq, bq, Wk, bk, Wv, bv, Wo, bo, out, total);
}